// Round 1
// 183.976 us; speedup vs baseline: 1.0231x; 1.0231x over previous
//
#include <hip/hip_runtime.h>
#include <hip/hip_bf16.h>
#include <stdint.h>
#include <type_traits>

// Problem constants
#define B_    2
#define HW_   4096
#define NTGT_ 4096
#define C_    512
#define H_    8
#define KNN_  32
#define DH_   64
#define M_    (B_ * HW_)

typedef unsigned short ushort_t;
typedef __bf16 bf16x8 __attribute__((ext_vector_type(8)));
typedef float floatx4 __attribute__((ext_vector_type(4)));

__device__ __forceinline__ float b2f(ushort_t u) {
    union { uint32_t i; float f; } x;
    x.i = ((uint32_t)u) << 16;
    return x.f;
}
__device__ __forceinline__ ushort_t f2b(float f) {
    union { float f; uint32_t i; } x;
    x.f = f;
    uint32_t r = x.i + 0x7fffu + ((x.i >> 16) & 1u);
    return (ushort_t)(r >> 16);
}
// HW packed fp32x2 -> bf16x2 (v_cvt_pk_bf16_f32)
__device__ __forceinline__ uint32_t pk2(float x, float y) {
    union { __hip_bfloat162 h2; uint32_t u; } c;
    c.h2 = __float22bfloat162_rn(make_float2(x, y));
    return c.u;
}
__device__ __forceinline__ uint4 pack8(const float4& a, const float4& b) {
    return make_uint4(pk2(a.x, a.y), pk2(a.z, a.w), pk2(b.x, b.y), pk2(b.z, b.w));
}

// ---------------------------------------------------------------------------
// Out-of-place transpose+convert: T_bf16[n][k] = W_fp32[k][n], 4 matrices.
// No input mutation. grid (16,16,4).
// ---------------------------------------------------------------------------
__global__ __launch_bounds__(256) void transpose_cvt4(
    const float* __restrict__ W0, const float* __restrict__ W1,
    const float* __restrict__ W2, const float* __restrict__ W3,
    ushort_t* __restrict__ T0, ushort_t* __restrict__ T1,
    ushort_t* __restrict__ T2, ushort_t* __restrict__ T3) {
    __shared__ float tile[32][33];

    const float* W = (blockIdx.z == 0) ? W0 : (blockIdx.z == 1) ? W1
                     : (blockIdx.z == 2) ? W2 : W3;
    ushort_t* T = (blockIdx.z == 0) ? T0 : (blockIdx.z == 1) ? T1
                  : (blockIdx.z == 2) ? T2 : T3;

    const int k0 = blockIdx.x * 32;
    const int n0 = blockIdx.y * 32;
    const int t = threadIdx.x;
    const int r = t >> 3;
    const int c0 = (t & 7) * 4;

    float4 d = *(const float4*)&W[(size_t)(k0 + r) * 512 + n0 + c0];
    tile[r][c0 + 0] = d.x; tile[r][c0 + 1] = d.y;
    tile[r][c0 + 2] = d.z; tile[r][c0 + 3] = d.w;
    __syncthreads();

    uint2 o;
    o.x = pk2(tile[c0 + 0][r], tile[c0 + 1][r]);
    o.y = pk2(tile[c0 + 2][r], tile[c0 + 3][r]);
    *(uint2*)&T[(size_t)(n0 + r) * 512 + k0 + c0] = o;
}

// ---------------------------------------------------------------------------
// IN-PLACE fp32 transpose fallback (if ws can't hold bf16 weights).
// ---------------------------------------------------------------------------
__global__ __launch_bounds__(256) void transpose_inplace4_f32(
    float* W0, float* W1, float* W2, float* W3) {
    __shared__ float ta[32][33];
    __shared__ float tb[32][33];

    float* W = (blockIdx.y == 0) ? W0 : (blockIdx.y == 1) ? W1
               : (blockIdx.y == 2) ? W2 : W3;

    int p = blockIdx.x;
    int i = 0, acc = 0;
    while (acc + (16 - i) <= p) { acc += 16 - i; ++i; }
    const int j = i + (p - acc);

    const int t = threadIdx.x;
    const int r = t >> 3;
    const int c0 = (t & 7) * 4;

    {
        float4 d = *(const float4*)&W[(size_t)(i * 32 + r) * 512 + j * 32 + c0];
        ta[r][c0 + 0] = d.x; ta[r][c0 + 1] = d.y;
        ta[r][c0 + 2] = d.z; ta[r][c0 + 3] = d.w;
    }
    if (i != j) {
        float4 d = *(const float4*)&W[(size_t)(j * 32 + r) * 512 + i * 32 + c0];
        tb[r][c0 + 0] = d.x; tb[r][c0 + 1] = d.y;
        tb[r][c0 + 2] = d.z; tb[r][c0 + 3] = d.w;
    }
    __syncthreads();

    *(float4*)&W[(size_t)(j * 32 + r) * 512 + i * 32 + c0] =
        make_float4(ta[c0 + 0][r], ta[c0 + 1][r], ta[c0 + 2][r], ta[c0 + 3][r]);
    if (i != j)
        *(float4*)&W[(size_t)(i * 32 + r) * 512 + j * 32 + c0] =
            make_float4(tb[c0 + 0][r], tb[c0 + 1][r], tb[c0 + 2][r], tb[c0 + 3][r]);
}

// ---------------------------------------------------------------------------
// MFMA GEMM body: 128(M) x BN(N) tile, BK=32, prefetch-pipelined K-loop.
// 4 waves 2x2; wave region 64 x BN/2 -> 4 x (BN/32) MFMAs of 16x16x32 bf16.
// AT/BT = fp32 (cvt via v_cvt_pk_bf16_f32) or bf16 (pure uint4 copy).
// ---------------------------------------------------------------------------
template <typename AT, typename BT, typename OT, int BN>
__device__ __forceinline__ void gemm_body(const AT* __restrict__ A,
                                          const BT* __restrict__ Wt,
                                          const float* __restrict__ bias,
                                          OT* __restrict__ O,
                                          int bm, int bn) {
    constexpr int NJ = BN / 32;          // MFMAs in n per wave
    __shared__ ushort_t As[128][40];     // [m][k] bf16, 80B stride
    __shared__ ushort_t Bs[BN][40];      // [n][k] bf16

    const int t = threadIdx.x;
    const int lr = t >> 2;        // 0..63
    const int lc = (t & 3) * 8;   // 0,8,16,24

    const int lane = t & 63;
    const int wv = t >> 6;
    const int wr = (wv >> 1) * 64;
    const int wc = (wv & 1) * (BN / 2);
    const int r16 = lane & 15;
    const int quad = lane >> 4;

    floatx4 acc[4][NJ] = {};

    float4 fa0, fa1, fa2, fa3, fb0, fb1, fb2, fb3;
    uint4 ua0, ua1, ub0, ub1;

    // prefetch kt = 0
    if constexpr (std::is_same<AT, float>::value) {
        const float* p0 = &A[(size_t)(bm + lr) * 512 + lc];
        const float* p1 = &A[(size_t)(bm + lr + 64) * 512 + lc];
        fa0 = *(const float4*)p0; fa1 = *(const float4*)(p0 + 4);
        fa2 = *(const float4*)p1; fa3 = *(const float4*)(p1 + 4);
    } else {
        ua0 = *(const uint4*)&A[(size_t)(bm + lr) * 512 + lc];
        ua1 = *(const uint4*)&A[(size_t)(bm + lr + 64) * 512 + lc];
    }
    if constexpr (std::is_same<BT, float>::value) {
        const float* p0 = &Wt[(size_t)(bn + lr) * 512 + lc];
        fb0 = *(const float4*)p0; fb1 = *(const float4*)(p0 + 4);
        if constexpr (BN == 128) {
            const float* p1 = &Wt[(size_t)(bn + lr + 64) * 512 + lc];
            fb2 = *(const float4*)p1; fb3 = *(const float4*)(p1 + 4);
        }
    } else {
        ub0 = *(const uint4*)&Wt[(size_t)(bn + lr) * 512 + lc];
        if constexpr (BN == 128)
            ub1 = *(const uint4*)&Wt[(size_t)(bn + lr + 64) * 512 + lc];
    }

    for (int kt = 0; kt < 512; kt += 32) {
        __syncthreads();  // prior iteration's fragment reads complete
        if constexpr (std::is_same<AT, float>::value) {
            *(uint4*)&As[lr][lc] = pack8(fa0, fa1);
            *(uint4*)&As[lr + 64][lc] = pack8(fa2, fa3);
        } else {
            *(uint4*)&As[lr][lc] = ua0;
            *(uint4*)&As[lr + 64][lc] = ua1;
        }
        if constexpr (std::is_same<BT, float>::value) {
            *(uint4*)&Bs[lr][lc] = pack8(fb0, fb1);
            if constexpr (BN == 128) *(uint4*)&Bs[lr + 64][lc] = pack8(fb2, fb3);
        } else {
            *(uint4*)&Bs[lr][lc] = ub0;
            if constexpr (BN == 128) *(uint4*)&Bs[lr + 64][lc] = ub1;
        }
        __syncthreads();

        if (kt + 32 < 512) {  // issue next-tile loads; wait lands at publish
            const int k2 = kt + 32;
            if constexpr (std::is_same<AT, float>::value) {
                const float* p0 = &A[(size_t)(bm + lr) * 512 + k2 + lc];
                const float* p1 = &A[(size_t)(bm + lr + 64) * 512 + k2 + lc];
                fa0 = *(const float4*)p0; fa1 = *(const float4*)(p0 + 4);
                fa2 = *(const float4*)p1; fa3 = *(const float4*)(p1 + 4);
            } else {
                ua0 = *(const uint4*)&A[(size_t)(bm + lr) * 512 + k2 + lc];
                ua1 = *(const uint4*)&A[(size_t)(bm + lr + 64) * 512 + k2 + lc];
            }
            if constexpr (std::is_same<BT, float>::value) {
                const float* p0 = &Wt[(size_t)(bn + lr) * 512 + k2 + lc];
                fb0 = *(const float4*)p0; fb1 = *(const float4*)(p0 + 4);
                if constexpr (BN == 128) {
                    const float* p1 = &Wt[(size_t)(bn + lr + 64) * 512 + k2 + lc];
                    fb2 = *(const float4*)p1; fb3 = *(const float4*)(p1 + 4);
                }
            } else {
                ub0 = *(const uint4*)&Wt[(size_t)(bn + lr) * 512 + k2 + lc];
                if constexpr (BN == 128)
                    ub1 = *(const uint4*)&Wt[(size_t)(bn + lr + 64) * 512 + k2 + lc];
            }
        }

        bf16x8 af[4], bf[NJ];
#pragma unroll
        for (int i = 0; i < 4; ++i)
            af[i] = *(const bf16x8*)&As[wr + i * 16 + r16][quad * 8];
#pragma unroll
        for (int j = 0; j < NJ; ++j)
            bf[j] = *(const bf16x8*)&Bs[wc + j * 16 + r16][quad * 8];
#pragma unroll
        for (int i = 0; i < 4; ++i)
#pragma unroll
            for (int j = 0; j < NJ; ++j)
                acc[i][j] = __builtin_amdgcn_mfma_f32_16x16x32_bf16(
                    af[i], bf[j], acc[i][j], 0, 0, 0);
    }

    // D layout: col=lane&15, row=quad*4+reg [m89]
#pragma unroll
    for (int j = 0; j < NJ; ++j) {
        const int col = bn + wc + j * 16 + r16;
        const float bj = bias[col];
#pragma unroll
        for (int i = 0; i < 4; ++i) {
            const int row = bm + wr + i * 16 + quad * 4;
#pragma unroll
            for (int r = 0; r < 4; ++r) {
                float v = acc[i][j][r] + bj;
                if constexpr (std::is_same<OT, ushort_t>::value)
                    O[(size_t)(row + r) * 512 + col] = f2b(v);
                else
                    O[(size_t)(row + r) * 512 + col] = v;
            }
        }
    }
}

// Fused Q/K/V projection: 128x128 tiles, XCD-swizzled 1D grid of 768 blocks.
// xcd = id&7 owns m-tiles {xcd, xcd+8, ...}: all 12 (n,z) tiles of an m-tile
// stay on one XCD.
template <typename BT>
__global__ __launch_bounds__(256, 3) void gemm_qkv(
    const float* __restrict__ src, const float* __restrict__ tgt,
    const BT* __restrict__ WtQ, const BT* __restrict__ WtK,
    const BT* __restrict__ WtV,
    const float* __restrict__ bq, const float* __restrict__ bk,
    const float* __restrict__ bv,
    ushort_t* __restrict__ Qb, ushort_t* __restrict__ Kb,
    ushort_t* __restrict__ Vb) {
    const int id = blockIdx.x;
    const int xcd = id & 7;
    const int g = id >> 3;        // 0..95
    const int mgrp = g / 12;      // 0..7
    const int r = g % 12;
    const int z = r >> 2;         // 0..2
    const int bn = (r & 3) * 128;
    const int bm = (xcd + 8 * mgrp) * 128;

    const float* A = (z == 0) ? src : tgt;
    const BT* Wt = (z == 0) ? WtQ : (z == 1) ? WtK : WtV;
    const float* bias = (z == 0) ? bq : (z == 1) ? bk : bv;
    ushort_t* O = (z == 0) ? Qb : (z == 1) ? Kb : Vb;
    gemm_body<float, BT, ushort_t, 128>(A, Wt, bias, O, bm, bn);
}

// Output projection: 128x64 tiles, XCD-swizzled 1D grid of 512 blocks.
template <typename BT, typename OT>
__global__ __launch_bounds__(256, 4) void gemm_o(const ushort_t* __restrict__ A,
                                                 const BT* __restrict__ Wt,
                                                 const float* __restrict__ bias,
                                                 OT* __restrict__ O) {
    const int id = blockIdx.x;
    const int xcd = id & 7;
    const int g = id >> 3;        // 0..63
    const int mgrp = g >> 3;      // 0..7
    const int bn = (g & 7) * 64;
    const int bm = (xcd + 8 * mgrp) * 128;
    gemm_body<ushort_t, BT, OT, 64>(A, Wt, bias, O, bm, bn);
}

// ---------------------------------------------------------------------------
// Gather attention — v2: 16-row sub-phases + register prefetch pipeline.
// LDS 20.1 KB/block (was 36.9) -> 7 blocks/CU (was 4); each gather's HBM
// latency is issued one phase early and hidden under the previous phase's
// dot/PV compute. Thread map for dots: (h = t>>5, nl = t&15, half = (t>>4)&1),
// 32-elem partial dot combined by one shfl_xor(16); softmax runs on the
// 2x-duplicated lanes (sum is exactly 2x -> inv = 2/s).
// O aliases Q (same-row only). XCD batch swizzle unchanged.
// ---------------------------------------------------------------------------
#define KVSTRIDE 520
template <typename IT>
__global__ __launch_bounds__(256, 7) void attn_kernel(const ushort_t* Q,
                                                      const ushort_t* __restrict__ K,
                                                      const ushort_t* __restrict__ V,
                                                      const IT* __restrict__ idx,
                                                      const float* __restrict__ wts,
                                                      ushort_t* O) {
    __shared__ float qs[16][34];            // q[h*64+half*32+d] at qs[h*2+half][d]
    __shared__ ushort_t kvs[16][KVSTRIDE];  // 16-row staging buffer
    __shared__ float ps[H_][KNN_];
    __shared__ int idxs[KNN_];
    __shared__ float ws[KNN_];

    const int t = threadIdx.x;
    const int id = blockIdx.x;
    const int xcd = id & 7;
    const int slot = id >> 3;
    const int b = xcd >> 2;
    const int bq = b * HW_ + (xcd & 3) * 1024 + slot;
    const size_t qoff = (size_t)bq * C_;

    {
        uint32_t d = *(const uint32_t*)(Q + qoff + 2 * t);
        const int qr = t >> 4, qc = (t & 15) * 2;
        qs[qr][qc + 0] = b2f((ushort_t)(d & 0xffffu));
        qs[qr][qc + 1] = b2f((ushort_t)(d >> 16));
    }
    if (t < KNN_) {
        idxs[t] = (int)idx[(size_t)bq * KNN_ + t];
        ws[t] = wts[(size_t)bq * KNN_ + t];
    }
    __syncthreads();  // (1) idxs/ws/qs ready

    const ushort_t* Kbase = K + (size_t)b * NTGT_ * C_;
    const ushort_t* Vbase = V + (size_t)b * NTGT_ * C_;
    const int prow = t >> 4;          // staging row 0..15 (16 lanes/row)
    const int pcol = (t & 15) * 8;    // element offset; +j*128 covers 512

    uint4 r0, r1, r2, r3;
    // K rows 0-15 -> regs -> LDS
    {
        const ushort_t* p = Kbase + (size_t)idxs[prow] * C_ + pcol;
        r0 = *(const uint4*)(p);       r1 = *(const uint4*)(p + 128);
        r2 = *(const uint4*)(p + 256); r3 = *(const uint4*)(p + 384);
    }
    *(uint4*)&kvs[prow][pcol + 0]   = r0;
    *(uint4*)&kvs[prow][pcol + 128] = r1;
    *(uint4*)&kvs[prow][pcol + 256] = r2;
    *(uint4*)&kvs[prow][pcol + 384] = r3;
    // issue K rows 16-31 early (latency hides under dot phase A)
    {
        const ushort_t* p = Kbase + (size_t)idxs[prow + 16] * C_ + pcol;
        r0 = *(const uint4*)(p);       r1 = *(const uint4*)(p + 128);
        r2 = *(const uint4*)(p + 256); r3 = *(const uint4*)(p + 384);
    }
    __syncthreads();  // (2) K rows 0-15 staged

    const int h = t >> 5;
    const int l5 = t & 31;
    const int nl = l5 & 15;
    const int half = l5 >> 4;
    const float* qh = qs[h * 2 + half];
    const int koff = h * 64 + half * 32;

    float l0, l1;
    {
        float dot = 0.f;
#pragma unroll
        for (int j = 0; j < 4; ++j) {
            uint4 kv = *(const uint4*)&kvs[nl][koff + j * 8];
            const int d0 = j * 8;
            dot = fmaf(qh[d0 + 0], b2f((ushort_t)(kv.x & 0xffffu)), dot);
            dot = fmaf(qh[d0 + 1], b2f((ushort_t)(kv.x >> 16)), dot);
            dot = fmaf(qh[d0 + 2], b2f((ushort_t)(kv.y & 0xffffu)), dot);
            dot = fmaf(qh[d0 + 3], b2f((ushort_t)(kv.y >> 16)), dot);
            dot = fmaf(qh[d0 + 4], b2f((ushort_t)(kv.z & 0xffffu)), dot);
            dot = fmaf(qh[d0 + 5], b2f((ushort_t)(kv.z >> 16)), dot);
            dot = fmaf(qh[d0 + 6], b2f((ushort_t)(kv.w & 0xffffu)), dot);
            dot = fmaf(qh[d0 + 7], b2f((ushort_t)(kv.w >> 16)), dot);
        }
        dot += __shfl_xor(dot, 16);   // combine halves: full 64-elem dot
        l0 = dot * 0.125f + ws[nl];
    }
    __syncthreads();  // (3) K-A reads complete
    // publish K rows 16-31; issue V rows 0-15
    *(uint4*)&kvs[prow][pcol + 0]   = r0;
    *(uint4*)&kvs[prow][pcol + 128] = r1;
    *(uint4*)&kvs[prow][pcol + 256] = r2;
    *(uint4*)&kvs[prow][pcol + 384] = r3;
    {
        const ushort_t* p = Vbase + (size_t)idxs[prow] * C_ + pcol;
        r0 = *(const uint4*)(p);       r1 = *(const uint4*)(p + 128);
        r2 = *(const uint4*)(p + 256); r3 = *(const uint4*)(p + 384);
    }
    __syncthreads();  // (4) K rows 16-31 staged
    {
        float dot = 0.f;
#pragma unroll
        for (int j = 0; j < 4; ++j) {
            uint4 kv = *(const uint4*)&kvs[nl][koff + j * 8];
            const int d0 = j * 8;
            dot = fmaf(qh[d0 + 0], b2f((ushort_t)(kv.x & 0xffffu)), dot);
            dot = fmaf(qh[d0 + 1], b2f((ushort_t)(kv.x >> 16)), dot);
            dot = fmaf(qh[d0 + 2], b2f((ushort_t)(kv.y & 0xffffu)), dot);
            dot = fmaf(qh[d0 + 3], b2f((ushort_t)(kv.y >> 16)), dot);
            dot = fmaf(qh[d0 + 4], b2f((ushort_t)(kv.z & 0xffffu)), dot);
            dot = fmaf(qh[d0 + 5], b2f((ushort_t)(kv.z >> 16)), dot);
            dot = fmaf(qh[d0 + 6], b2f((ushort_t)(kv.w & 0xffffu)), dot);
            dot = fmaf(qh[d0 + 7], b2f((ushort_t)(kv.w >> 16)), dot);
        }
        dot += __shfl_xor(dot, 16);
        l1 = dot * 0.125f + ws[nl + 16];
    }
    // softmax over 32 logits; each n present in exactly 2 lanes of the group
    {
        float m = fmaxf(l0, l1);
#pragma unroll
        for (int o = 16; o > 0; o >>= 1) m = fmaxf(m, __shfl_xor(m, o));
        float e0 = __expf(l0 - m), e1 = __expf(l1 - m);
        float s = e0 + e1;
#pragma unroll
        for (int o = 16; o > 0; o >>= 1) s += __shfl_xor(s, o);
        const float inv = 2.0f / s;   // duplicates double-count: exact /2
        ps[h][nl] = e0 * inv;         // duplicate lanes write same value
        ps[h][nl + 16] = e1 * inv;
    }
    __syncthreads();  // (5) K-B reads + ps writes complete
    // publish V rows 0-15; issue V rows 16-31
    *(uint4*)&kvs[prow][pcol + 0]   = r0;
    *(uint4*)&kvs[prow][pcol + 128] = r1;
    *(uint4*)&kvs[prow][pcol + 256] = r2;
    *(uint4*)&kvs[prow][pcol + 384] = r3;
    {
        const ushort_t* p = Vbase + (size_t)idxs[prow + 16] * C_ + pcol;
        r0 = *(const uint4*)(p);       r1 = *(const uint4*)(p + 128);
        r2 = *(const uint4*)(p + 256); r3 = *(const uint4*)(p + 384);
    }
    __syncthreads();  // (6) V rows 0-15 staged

    const int d2 = l5 * 2;
    float a0 = 0.f, a1 = 0.f;
#pragma unroll
    for (int nn = 0; nn < 16; ++nn) {
        uint32_t vv = *(const uint32_t*)&kvs[nn][h * DH_ + d2];
        float p = ps[h][nn];
        a0 = fmaf(p, b2f((ushort_t)(vv & 0xffffu)), a0);
        a1 = fmaf(p, b2f((ushort_t)(vv >> 16)), a1);
    }
    __syncthreads();  // (7) V-A reads complete
    *(uint4*)&kvs[prow][pcol + 0]   = r0;
    *(uint4*)&kvs[prow][pcol + 128] = r1;
    *(uint4*)&kvs[prow][pcol + 256] = r2;
    *(uint4*)&kvs[prow][pcol + 384] = r3;
    __syncthreads();  // (8) V rows 16-31 staged
#pragma unroll
    for (int nn = 0; nn < 16; ++nn) {
        uint32_t vv = *(const uint32_t*)&kvs[nn][h * DH_ + d2];
        float p = ps[h][nn + 16];
        a0 = fmaf(p, b2f((ushort_t)(vv & 0xffffu)), a0);
        a1 = fmaf(p, b2f((ushort_t)(vv >> 16)), a1);
    }
    *(uint32_t*)(O + qoff + h * DH_ + d2) = pk2(a0, a1);
}

// ---------------------------------------------------------------------------
static int elem_bytes(const void* p, size_t n, int dflt) {
    size_t sz = 0;
    hipError_t err = hipPointerGetAttribute(
        &sz, HIP_POINTER_ATTRIBUTE_RANGE_SIZE, (hipDeviceptr_t)(uintptr_t)p);
    if (err == hipSuccess && sz >= n && (sz % n) == 0) {
        size_t b = sz / n;
        if (b == 2 || b == 4 || b == 8) return (int)b;
    }
    return dflt;
}

extern "C" void kernel_launch(void* const* d_in, const int* in_sizes, int n_in,
                              void* d_out, int out_size, void* d_ws, size_t ws_size,
                              hipStream_t stream) {
    const float* src  = (const float*)d_in[0];
    const float* tgt  = (const float*)d_in[1];
    const void*  idxp = d_in[2];
    const float* wtp  = (const float*)d_in[3];
    float* Wq = (float*)d_in[4];  const float* bq = (const float*)d_in[5];
    float* Wk = (float*)d_in[6];  const float* bk = (const float*)d_in[7];
    float* Wv = (float*)d_in[8];  const float* bv = (const float*)d_in[9];
    float* Wo = (float*)d_in[10]; const float* bo = (const float*)d_in[11];

    const size_t NELEM = (size_t)M_ * C_;          // 4,194,304
    const size_t WELEM = (size_t)C_ * C_;          // 262,144
    const size_t NIDX  = (size_t)B_ * HW_ * KNN_;

    const int ib = elem_bytes(idxp, NIDX, 4);
    const int ob = elem_bytes(d_out, NELEM, 4);

    dim3 blk(256);

    // ws: Q bf16 [0,8MB) | K bf16 [8,16MB) | optional bf16 Wt x4 [16,18MB).
    // V bf16 in d_out (consumed by attn before gemm_o overwrites);
    // attn output aliases Q.
    ushort_t* Qb = (ushort_t*)d_ws;
    ushort_t* Kb = Qb + NELEM;
    ushort_t* Vb = (ushort_t*)d_out;
    ushort_t* Ob = Qb;

    const bool wfit = ws_size >= (2 * NELEM + 4 * WELEM) * sizeof(ushort_t);

    if (wfit) {
        // bf16 transposed weights in ws tail (no input mutation)
        ushort_t* T = Kb + NELEM;
        ushort_t* WtQ = T;
        ushort_t* WtK = T + WELEM;
        ushort_t* WtV = T + 2 * WELEM;
        ushort_t* WtO = T + 3 * WELEM;

        transpose_cvt4<<<dim3(16, 16, 4), blk, 0, stream>>>(
            Wq, Wk, Wv, Wo, WtQ, WtK, WtV, WtO);

        gemm_qkv<ushort_t><<<dim3(768), blk, 0, stream>>>(
            src, tgt, WtQ, WtK, WtV, bq, bk, bv, Qb, Kb, Vb);

        if (ib == 8)
            attn_kernel<long long><<<dim3(B_ * HW_), blk, 0, stream>>>(
                Qb, Kb, Vb, (const long long*)idxp, wtp, Ob);
        else
            attn_kernel<int><<<dim3(B_ * HW_), blk, 0, stream>>>(
                Qb, Kb, Vb, (const int*)idxp, wtp, Ob);

        if (ob == 2)
            gemm_o<ushort_t, ushort_t><<<dim3(512), blk, 0, stream>>>(
                Ob, WtO, bo, (ushort_t*)d_out);
        else
            gemm_o<ushort_t, float><<<dim3(512), blk, 0, stream>>>(
                Ob, WtO, bo, (float*)d_out);
    } else {
        // fallback: in-place fp32 transpose, fp32-B GEMMs (R8 semantics)
        transpose_inplace4_f32<<<dim3(136, 4), blk, 0, stream>>>(Wq, Wk, Wv, Wo);

        gemm_qkv<float><<<dim3(768), blk, 0, stream>>>(
            src, tgt, Wq, Wk, Wv, bq, bk, bv, Qb, Kb, Vb);

        if (ib == 8)
            attn_kernel<long long><<<dim3(B_ * HW_), blk, 0, stream>>>(
                Qb, Kb, Vb, (const long long*)idxp, wtp, Ob);
        else
            attn_kernel<int><<<dim3(B_ * HW_), blk, 0, stream>>>(
                Qb, Kb, Vb, (const int*)idxp, wtp, Ob);

        if (ob == 2)
            gemm_o<float, ushort_t><<<dim3(512), blk, 0, stream>>>(
                Ob, Wo, bo, (ushort_t*)d_out);
        else
            gemm_o<float, float><<<dim3(512), blk, 0, stream>>>(
                Ob, Wo, bo, (float*)d_out);
    }
}

// Round 3
// 181.916 us; speedup vs baseline: 1.0347x; 1.0113x over previous
//
#include <hip/hip_runtime.h>
#include <hip/hip_bf16.h>
#include <stdint.h>
#include <type_traits>

// Problem constants
#define B_    2
#define HW_   4096
#define NTGT_ 4096
#define C_    512
#define H_    8
#define KNN_  32
#define DH_   64
#define M_    (B_ * HW_)

typedef unsigned short ushort_t;
typedef _Float16 f16x8 __attribute__((ext_vector_type(8)));
typedef __fp16 hf2 __attribute__((ext_vector_type(2)));
typedef float floatx4 __attribute__((ext_vector_type(4)));

// ---- fp16 helpers (intermediates are IEEE fp16: more mantissa than bf16)
__device__ __forceinline__ uint32_t pkh(float x, float y) {
    union { hf2 h; uint32_t u; } c;
    c.h = __builtin_amdgcn_cvt_pkrtz(x, y);   // v_cvt_pkrtz_f16_f32
    return c.u;
}
__device__ __forceinline__ ushort_t f2h(float f) {
    return (ushort_t)(pkh(f, 0.f) & 0xffffu);
}
__device__ __forceinline__ float h2f(ushort_t u) {
    union { ushort_t s; __fp16 h; } x;
    x.s = u;
    return (float)x.h;                         // v_cvt_f32_f16
}
// bf16 round-to-nearest (final-output defensive path only)
__device__ __forceinline__ ushort_t f2b(float f) {
    union { float f; uint32_t i; } x;
    x.f = f;
    uint32_t r = x.i + 0x7fffu + ((x.i >> 16) & 1u);
    return (ushort_t)(r >> 16);
}
// 2-way fp16 dot with f32 accumulate: v_dot2_f32_f16
__device__ __forceinline__ float dot2acc(uint32_t a, uint32_t b, float c) {
#if __has_builtin(__builtin_amdgcn_fdot2)
    union { uint32_t u; hf2 h; } xa, xb;
    xa.u = a; xb.u = b;
    return __builtin_amdgcn_fdot2(xa.h, xb.h, c, false);
#else
    c = fmaf(h2f((ushort_t)(a & 0xffffu)), h2f((ushort_t)(b & 0xffffu)), c);
    return fmaf(h2f((ushort_t)(a >> 16)), h2f((ushort_t)(b >> 16)), c);
#endif
}
__device__ __forceinline__ uint4 pack8(const float4& a, const float4& b) {
    return make_uint4(pkh(a.x, a.y), pkh(a.z, a.w), pkh(b.x, b.y), pkh(b.z, b.w));
}

// ---------------------------------------------------------------------------
// Out-of-place transpose+convert: T_fp16[n][k] = W_fp32[k][n], 4 matrices.
// No input mutation. grid (16,16,4).
// ---------------------------------------------------------------------------
__global__ __launch_bounds__(256) void transpose_cvt4(
    const float* __restrict__ W0, const float* __restrict__ W1,
    const float* __restrict__ W2, const float* __restrict__ W3,
    ushort_t* __restrict__ T0, ushort_t* __restrict__ T1,
    ushort_t* __restrict__ T2, ushort_t* __restrict__ T3) {
    __shared__ float tile[32][33];

    const float* W = (blockIdx.z == 0) ? W0 : (blockIdx.z == 1) ? W1
                     : (blockIdx.z == 2) ? W2 : W3;
    ushort_t* T = (blockIdx.z == 0) ? T0 : (blockIdx.z == 1) ? T1
                  : (blockIdx.z == 2) ? T2 : T3;

    const int k0 = blockIdx.x * 32;
    const int n0 = blockIdx.y * 32;
    const int t = threadIdx.x;
    const int r = t >> 3;
    const int c0 = (t & 7) * 4;

    float4 d = *(const float4*)&W[(size_t)(k0 + r) * 512 + n0 + c0];
    tile[r][c0 + 0] = d.x; tile[r][c0 + 1] = d.y;
    tile[r][c0 + 2] = d.z; tile[r][c0 + 3] = d.w;
    __syncthreads();

    uint2 o;
    o.x = pkh(tile[c0 + 0][r], tile[c0 + 1][r]);
    o.y = pkh(tile[c0 + 2][r], tile[c0 + 3][r]);
    *(uint2*)&T[(size_t)(n0 + r) * 512 + k0 + c0] = o;
}

// ---------------------------------------------------------------------------
// IN-PLACE fp32 transpose fallback (if ws can't hold fp16 weights).
// ---------------------------------------------------------------------------
__global__ __launch_bounds__(256) void transpose_inplace4_f32(
    float* W0, float* W1, float* W2, float* W3) {
    __shared__ float ta[32][33];
    __shared__ float tb[32][33];

    float* W = (blockIdx.y == 0) ? W0 : (blockIdx.y == 1) ? W1
               : (blockIdx.y == 2) ? W2 : W3;

    int p = blockIdx.x;
    int i = 0, acc = 0;
    while (acc + (16 - i) <= p) { acc += 16 - i; ++i; }
    const int j = i + (p - acc);

    const int t = threadIdx.x;
    const int r = t >> 3;
    const int c0 = (t & 7) * 4;

    {
        float4 d = *(const float4*)&W[(size_t)(i * 32 + r) * 512 + j * 32 + c0];
        ta[r][c0 + 0] = d.x; ta[r][c0 + 1] = d.y;
        ta[r][c0 + 2] = d.z; ta[r][c0 + 3] = d.w;
    }
    if (i != j) {
        float4 d = *(const float4*)&W[(size_t)(j * 32 + r) * 512 + i * 32 + c0];
        tb[r][c0 + 0] = d.x; tb[r][c0 + 1] = d.y;
        tb[r][c0 + 2] = d.z; tb[r][c0 + 3] = d.w;
    }
    __syncthreads();

    *(float4*)&W[(size_t)(j * 32 + r) * 512 + i * 32 + c0] =
        make_float4(ta[c0 + 0][r], ta[c0 + 1][r], ta[c0 + 2][r], ta[c0 + 3][r]);
    if (i != j)
        *(float4*)&W[(size_t)(i * 32 + r) * 512 + j * 32 + c0] =
            make_float4(tb[c0 + 0][r], tb[c0 + 1][r], tb[c0 + 2][r], tb[c0 + 3][r]);
}

// ---------------------------------------------------------------------------
// MFMA GEMM body: 128(M) x BN(N) tile, BK=32, prefetch-pipelined K-loop.
// 4 waves 2x2; wave region 64 x BN/2 -> 4 x (BN/32) MFMAs of 16x16x32 f16.
// AT = fp32 (cvt via v_cvt_pkrtz) or 16-bit raw. Output: f32 / fp16 / bf16.
// ---------------------------------------------------------------------------
template <typename AT, typename BT, typename OT, int BN, bool OBF16>
__device__ __forceinline__ void gemm_body(const AT* __restrict__ A,
                                          const BT* __restrict__ Wt,
                                          const float* __restrict__ bias,
                                          OT* __restrict__ O,
                                          int bm, int bn) {
    constexpr int NJ = BN / 32;          // MFMAs in n per wave
    __shared__ ushort_t As[128][40];     // [m][k] fp16, 80B stride
    __shared__ ushort_t Bs[BN][40];      // [n][k] fp16

    const int t = threadIdx.x;
    const int lr = t >> 2;        // 0..63
    const int lc = (t & 3) * 8;   // 0,8,16,24

    const int lane = t & 63;
    const int wv = t >> 6;
    const int wr = (wv >> 1) * 64;
    const int wc = (wv & 1) * (BN / 2);
    const int r16 = lane & 15;
    const int quad = lane >> 4;

    floatx4 acc[4][NJ] = {};

    float4 fa0, fa1, fa2, fa3, fb0, fb1, fb2, fb3;
    uint4 ua0, ua1, ub0, ub1;

    // prefetch kt = 0
    if constexpr (std::is_same<AT, float>::value) {
        const float* p0 = &A[(size_t)(bm + lr) * 512 + lc];
        const float* p1 = &A[(size_t)(bm + lr + 64) * 512 + lc];
        fa0 = *(const float4*)p0; fa1 = *(const float4*)(p0 + 4);
        fa2 = *(const float4*)p1; fa3 = *(const float4*)(p1 + 4);
    } else {
        ua0 = *(const uint4*)&A[(size_t)(bm + lr) * 512 + lc];
        ua1 = *(const uint4*)&A[(size_t)(bm + lr + 64) * 512 + lc];
    }
    if constexpr (std::is_same<BT, float>::value) {
        const float* p0 = &Wt[(size_t)(bn + lr) * 512 + lc];
        fb0 = *(const float4*)p0; fb1 = *(const float4*)(p0 + 4);
        if constexpr (BN == 128) {
            const float* p1 = &Wt[(size_t)(bn + lr + 64) * 512 + lc];
            fb2 = *(const float4*)p1; fb3 = *(const float4*)(p1 + 4);
        }
    } else {
        ub0 = *(const uint4*)&Wt[(size_t)(bn + lr) * 512 + lc];
        if constexpr (BN == 128)
            ub1 = *(const uint4*)&Wt[(size_t)(bn + lr + 64) * 512 + lc];
    }

    for (int kt = 0; kt < 512; kt += 32) {
        __syncthreads();  // prior iteration's fragment reads complete
        if constexpr (std::is_same<AT, float>::value) {
            *(uint4*)&As[lr][lc] = pack8(fa0, fa1);
            *(uint4*)&As[lr + 64][lc] = pack8(fa2, fa3);
        } else {
            *(uint4*)&As[lr][lc] = ua0;
            *(uint4*)&As[lr + 64][lc] = ua1;
        }
        if constexpr (std::is_same<BT, float>::value) {
            *(uint4*)&Bs[lr][lc] = pack8(fb0, fb1);
            if constexpr (BN == 128) *(uint4*)&Bs[lr + 64][lc] = pack8(fb2, fb3);
        } else {
            *(uint4*)&Bs[lr][lc] = ub0;
            if constexpr (BN == 128) *(uint4*)&Bs[lr + 64][lc] = ub1;
        }
        __syncthreads();

        if (kt + 32 < 512) {  // issue next-tile loads; wait lands at publish
            const int k2 = kt + 32;
            if constexpr (std::is_same<AT, float>::value) {
                const float* p0 = &A[(size_t)(bm + lr) * 512 + k2 + lc];
                const float* p1 = &A[(size_t)(bm + lr + 64) * 512 + k2 + lc];
                fa0 = *(const float4*)p0; fa1 = *(const float4*)(p0 + 4);
                fa2 = *(const float4*)p1; fa3 = *(const float4*)(p1 + 4);
            } else {
                ua0 = *(const uint4*)&A[(size_t)(bm + lr) * 512 + k2 + lc];
                ua1 = *(const uint4*)&A[(size_t)(bm + lr + 64) * 512 + k2 + lc];
            }
            if constexpr (std::is_same<BT, float>::value) {
                const float* p0 = &Wt[(size_t)(bn + lr) * 512 + k2 + lc];
                fb0 = *(const float4*)p0; fb1 = *(const float4*)(p0 + 4);
                if constexpr (BN == 128) {
                    const float* p1 = &Wt[(size_t)(bn + lr + 64) * 512 + k2 + lc];
                    fb2 = *(const float4*)p1; fb3 = *(const float4*)(p1 + 4);
                }
            } else {
                ub0 = *(const uint4*)&Wt[(size_t)(bn + lr) * 512 + k2 + lc];
                if constexpr (BN == 128)
                    ub1 = *(const uint4*)&Wt[(size_t)(bn + lr + 64) * 512 + k2 + lc];
            }
        }

        f16x8 af[4], bf[NJ];
#pragma unroll
        for (int i = 0; i < 4; ++i)
            af[i] = *(const f16x8*)&As[wr + i * 16 + r16][quad * 8];
#pragma unroll
        for (int j = 0; j < NJ; ++j)
            bf[j] = *(const f16x8*)&Bs[wc + j * 16 + r16][quad * 8];
#pragma unroll
        for (int i = 0; i < 4; ++i)
#pragma unroll
            for (int j = 0; j < NJ; ++j)
                acc[i][j] = __builtin_amdgcn_mfma_f32_16x16x32_f16(
                    af[i], bf[j], acc[i][j], 0, 0, 0);
    }

    // D layout: col=lane&15, row=quad*4+reg [m89]
#pragma unroll
    for (int j = 0; j < NJ; ++j) {
        const int col = bn + wc + j * 16 + r16;
        const float bj = bias[col];
#pragma unroll
        for (int i = 0; i < 4; ++i) {
            const int row = bm + wr + i * 16 + quad * 4;
#pragma unroll
            for (int r = 0; r < 4; ++r) {
                float v = acc[i][j][r] + bj;
                if constexpr (std::is_same<OT, float>::value)
                    O[(size_t)(row + r) * 512 + col] = v;
                else if constexpr (OBF16)
                    O[(size_t)(row + r) * 512 + col] = f2b(v);
                else
                    O[(size_t)(row + r) * 512 + col] = f2h(v);
            }
        }
    }
}

// Fused Q/K/V projection: 128x128 tiles, XCD-swizzled 1D grid of 768 blocks.
template <typename BT>
__global__ __launch_bounds__(256, 3) void gemm_qkv(
    const float* __restrict__ src, const float* __restrict__ tgt,
    const BT* __restrict__ WtQ, const BT* __restrict__ WtK,
    const BT* __restrict__ WtV,
    const float* __restrict__ bq, const float* __restrict__ bk,
    const float* __restrict__ bv,
    ushort_t* __restrict__ Qb, ushort_t* __restrict__ Kb,
    ushort_t* __restrict__ Vb) {
    const int id = blockIdx.x;
    const int xcd = id & 7;
    const int g = id >> 3;        // 0..95
    const int mgrp = g / 12;      // 0..7
    const int r = g % 12;
    const int z = r >> 2;         // 0..2
    const int bn = (r & 3) * 128;
    const int bm = (xcd + 8 * mgrp) * 128;

    const float* A = (z == 0) ? src : tgt;
    const BT* Wt = (z == 0) ? WtQ : (z == 1) ? WtK : WtV;
    const float* bias = (z == 0) ? bq : (z == 1) ? bk : bv;
    ushort_t* O = (z == 0) ? Qb : (z == 1) ? Kb : Vb;
    gemm_body<float, BT, ushort_t, 128, false>(A, Wt, bias, O, bm, bn);
}

// Output projection: 128x64 tiles, XCD-swizzled 1D grid of 512 blocks.
template <typename BT, typename OT, bool OBF16>
__global__ __launch_bounds__(256, 4) void gemm_o(const ushort_t* __restrict__ A,
                                                 const BT* __restrict__ Wt,
                                                 const float* __restrict__ bias,
                                                 OT* __restrict__ O) {
    const int id = blockIdx.x;
    const int xcd = id & 7;
    const int g = id >> 3;        // 0..63
    const int mgrp = g >> 3;      // 0..7
    const int bn = (g & 7) * 64;
    const int bm = (xcd + 8 * mgrp) * 128;
    gemm_body<ushort_t, BT, OT, 64, OBF16>(A, Wt, bias, O, bm, bn);
}

// ---------------------------------------------------------------------------
// Gather attention — v3: fp16 intermediates + v_dot2_f32_f16 dot phases.
// Structure identical to v2 (16-row sub-phases, register prefetch pipeline,
// 8 barriers). Q fragments hoisted into 16 VGPRs (4 x b128 LDS reads, reused
// across both dot phases). Dot phase per thread: 4 ds_read_b128 + 16 fdot2
// (was 4 reads + 32 lshl + 32 fma). PV keeps f32 accumulation.
// O aliases Q (same-row only). XCD batch swizzle unchanged.
// ---------------------------------------------------------------------------
#define KVSTRIDE 520
template <typename IT>
__global__ __launch_bounds__(256, 7) void attn_kernel(const ushort_t* Q,
                                                      const ushort_t* __restrict__ K,
                                                      const ushort_t* __restrict__ V,
                                                      const IT* __restrict__ idx,
                                                      const float* __restrict__ wts,
                                                      ushort_t* O) {
    __shared__ uint32_t qs[16][20];         // raw fp16 pairs; row=h*2+half
    __shared__ ushort_t kvs[16][KVSTRIDE];  // 16-row staging buffer
    __shared__ float ps[H_][KNN_];
    __shared__ int idxs[KNN_];
    __shared__ float ws[KNN_];

    const int t = threadIdx.x;
    const int id = blockIdx.x;
    const int xcd = id & 7;
    const int slot = id >> 3;
    const int b = xcd >> 2;
    const int bq = b * HW_ + (xcd & 3) * 1024 + slot;
    const size_t qoff = (size_t)bq * C_;

    // Q is fp16: raw pair copy, no conversion
    qs[t >> 4][t & 15] = *(const uint32_t*)(Q + qoff + 2 * t);
    if (t < KNN_) {
        idxs[t] = (int)idx[(size_t)bq * KNN_ + t];
        ws[t] = wts[(size_t)bq * KNN_ + t];
    }
    __syncthreads();  // (1) idxs/ws/qs ready

    const ushort_t* Kbase = K + (size_t)b * NTGT_ * C_;
    const ushort_t* Vbase = V + (size_t)b * NTGT_ * C_;
    const int prow = t >> 4;          // staging row 0..15 (16 lanes/row)
    const int pcol = (t & 15) * 8;    // element offset; +j*128 covers 512

    const int h = t >> 5;
    const int l5 = t & 31;
    const int nl = l5 & 15;
    const int half = l5 >> 4;
    const int koff = h * 64 + half * 32;

    uint4 r0, r1, r2, r3;
    // K rows 0-15 -> regs -> LDS
    {
        const ushort_t* p = Kbase + (size_t)idxs[prow] * C_ + pcol;
        r0 = *(const uint4*)(p);       r1 = *(const uint4*)(p + 128);
        r2 = *(const uint4*)(p + 256); r3 = *(const uint4*)(p + 384);
    }
    // hoist Q fragment into regs (LDS; independent counter from globals)
    const int qrow = h * 2 + half;
    uint4 q0 = *(const uint4*)&qs[qrow][0];
    uint4 q1 = *(const uint4*)&qs[qrow][4];
    uint4 q2 = *(const uint4*)&qs[qrow][8];
    uint4 q3 = *(const uint4*)&qs[qrow][12];

    *(uint4*)&kvs[prow][pcol + 0]   = r0;
    *(uint4*)&kvs[prow][pcol + 128] = r1;
    *(uint4*)&kvs[prow][pcol + 256] = r2;
    *(uint4*)&kvs[prow][pcol + 384] = r3;
    // issue K rows 16-31 early (latency hides under dot phase A)
    {
        const ushort_t* p = Kbase + (size_t)idxs[prow + 16] * C_ + pcol;
        r0 = *(const uint4*)(p);       r1 = *(const uint4*)(p + 128);
        r2 = *(const uint4*)(p + 256); r3 = *(const uint4*)(p + 384);
    }
    __syncthreads();  // (2) K rows 0-15 staged

    float l0, l1;
    {
        uint4 kv0 = *(const uint4*)&kvs[nl][koff + 0];
        uint4 kv1 = *(const uint4*)&kvs[nl][koff + 8];
        uint4 kv2 = *(const uint4*)&kvs[nl][koff + 16];
        uint4 kv3 = *(const uint4*)&kvs[nl][koff + 24];
        float da = 0.f, db = 0.f;
        da = dot2acc(kv0.x, q0.x, da); da = dot2acc(kv0.y, q0.y, da);
        da = dot2acc(kv0.z, q0.z, da); da = dot2acc(kv0.w, q0.w, da);
        db = dot2acc(kv1.x, q1.x, db); db = dot2acc(kv1.y, q1.y, db);
        db = dot2acc(kv1.z, q1.z, db); db = dot2acc(kv1.w, q1.w, db);
        da = dot2acc(kv2.x, q2.x, da); da = dot2acc(kv2.y, q2.y, da);
        da = dot2acc(kv2.z, q2.z, da); da = dot2acc(kv2.w, q2.w, da);
        db = dot2acc(kv3.x, q3.x, db); db = dot2acc(kv3.y, q3.y, db);
        db = dot2acc(kv3.z, q3.z, db); db = dot2acc(kv3.w, q3.w, db);
        float dot = da + db;
        dot += __shfl_xor(dot, 16);   // combine halves: full 64-elem dot
        l0 = dot * 0.125f + ws[nl];
    }
    __syncthreads();  // (3) K-A reads complete
    // publish K rows 16-31; issue V rows 0-15
    *(uint4*)&kvs[prow][pcol + 0]   = r0;
    *(uint4*)&kvs[prow][pcol + 128] = r1;
    *(uint4*)&kvs[prow][pcol + 256] = r2;
    *(uint4*)&kvs[prow][pcol + 384] = r3;
    {
        const ushort_t* p = Vbase + (size_t)idxs[prow] * C_ + pcol;
        r0 = *(const uint4*)(p);       r1 = *(const uint4*)(p + 128);
        r2 = *(const uint4*)(p + 256); r3 = *(const uint4*)(p + 384);
    }
    __syncthreads();  // (4) K rows 16-31 staged
    {
        uint4 kv0 = *(const uint4*)&kvs[nl][koff + 0];
        uint4 kv1 = *(const uint4*)&kvs[nl][koff + 8];
        uint4 kv2 = *(const uint4*)&kvs[nl][koff + 16];
        uint4 kv3 = *(const uint4*)&kvs[nl][koff + 24];
        float da = 0.f, db = 0.f;
        da = dot2acc(kv0.x, q0.x, da); da = dot2acc(kv0.y, q0.y, da);
        da = dot2acc(kv0.z, q0.z, da); da = dot2acc(kv0.w, q0.w, da);
        db = dot2acc(kv1.x, q1.x, db); db = dot2acc(kv1.y, q1.y, db);
        db = dot2acc(kv1.z, q1.z, db); db = dot2acc(kv1.w, q1.w, db);
        da = dot2acc(kv2.x, q2.x, da); da = dot2acc(kv2.y, q2.y, da);
        da = dot2acc(kv2.z, q2.z, da); da = dot2acc(kv2.w, q2.w, da);
        db = dot2acc(kv3.x, q3.x, db); db = dot2acc(kv3.y, q3.y, db);
        db = dot2acc(kv3.z, q3.z, db); db = dot2acc(kv3.w, q3.w, db);
        float dot = da + db;
        dot += __shfl_xor(dot, 16);
        l1 = dot * 0.125f + ws[nl + 16];
    }
    // softmax over 32 logits; each n present in exactly 2 lanes of the group
    {
        float m = fmaxf(l0, l1);
#pragma unroll
        for (int o = 16; o > 0; o >>= 1) m = fmaxf(m, __shfl_xor(m, o));
        float e0 = __expf(l0 - m), e1 = __expf(l1 - m);
        float s = e0 + e1;
#pragma unroll
        for (int o = 16; o > 0; o >>= 1) s += __shfl_xor(s, o);
        const float inv = 2.0f / s;   // duplicates double-count: exact /2
        ps[h][nl] = e0 * inv;         // duplicate lanes write same value
        ps[h][nl + 16] = e1 * inv;
    }
    __syncthreads();  // (5) K-B reads + ps writes complete
    // publish V rows 0-15; issue V rows 16-31
    *(uint4*)&kvs[prow][pcol + 0]   = r0;
    *(uint4*)&kvs[prow][pcol + 128] = r1;
    *(uint4*)&kvs[prow][pcol + 256] = r2;
    *(uint4*)&kvs[prow][pcol + 384] = r3;
    {
        const ushort_t* p = Vbase + (size_t)idxs[prow + 16] * C_ + pcol;
        r0 = *(const uint4*)(p);       r1 = *(const uint4*)(p + 128);
        r2 = *(const uint4*)(p + 256); r3 = *(const uint4*)(p + 384);
    }
    __syncthreads();  // (6) V rows 0-15 staged

    const int d2 = l5 * 2;
    float a0 = 0.f, a1 = 0.f;
#pragma unroll
    for (int nn = 0; nn < 16; ++nn) {
        uint32_t vv = *(const uint32_t*)&kvs[nn][h * DH_ + d2];
        float p = ps[h][nn];
        a0 = fmaf(p, h2f((ushort_t)(vv & 0xffffu)), a0);
        a1 = fmaf(p, h2f((ushort_t)(vv >> 16)), a1);
    }
    __syncthreads();  // (7) V-A reads complete
    *(uint4*)&kvs[prow][pcol + 0]   = r0;
    *(uint4*)&kvs[prow][pcol + 128] = r1;
    *(uint4*)&kvs[prow][pcol + 256] = r2;
    *(uint4*)&kvs[prow][pcol + 384] = r3;
    __syncthreads();  // (8) V rows 16-31 staged
#pragma unroll
    for (int nn = 0; nn < 16; ++nn) {
        uint32_t vv = *(const uint32_t*)&kvs[nn][h * DH_ + d2];
        float p = ps[h][nn + 16];
        a0 = fmaf(p, h2f((ushort_t)(vv & 0xffffu)), a0);
        a1 = fmaf(p, h2f((ushort_t)(vv >> 16)), a1);
    }
    *(uint32_t*)(O + qoff + h * DH_ + d2) = pkh(a0, a1);
}

// ---------------------------------------------------------------------------
static int elem_bytes(const void* p, size_t n, int dflt) {
    size_t sz = 0;
    hipError_t err = hipPointerGetAttribute(
        &sz, HIP_POINTER_ATTRIBUTE_RANGE_SIZE, (hipDeviceptr_t)(uintptr_t)p);
    if (err == hipSuccess && sz >= n && (sz % n) == 0) {
        size_t b = sz / n;
        if (b == 2 || b == 4 || b == 8) return (int)b;
    }
    return dflt;
}

extern "C" void kernel_launch(void* const* d_in, const int* in_sizes, int n_in,
                              void* d_out, int out_size, void* d_ws, size_t ws_size,
                              hipStream_t stream) {
    const float* src  = (const float*)d_in[0];
    const float* tgt  = (const float*)d_in[1];
    const void*  idxp = d_in[2];
    const float* wtp  = (const float*)d_in[3];
    float* Wq = (float*)d_in[4];  const float* bq = (const float*)d_in[5];
    float* Wk = (float*)d_in[6];  const float* bk = (const float*)d_in[7];
    float* Wv = (float*)d_in[8];  const float* bv = (const float*)d_in[9];
    float* Wo = (float*)d_in[10]; const float* bo = (const float*)d_in[11];

    const size_t NELEM = (size_t)M_ * C_;          // 4,194,304
    const size_t WELEM = (size_t)C_ * C_;          // 262,144
    const size_t NIDX  = (size_t)B_ * HW_ * KNN_;

    const int ib = elem_bytes(idxp, NIDX, 4);
    const int ob = elem_bytes(d_out, NELEM, 4);

    dim3 blk(256);

    // ws: Q fp16 [0,8MB) | K fp16 [8,16MB) | optional fp16 Wt x4 [16,18MB).
    // V fp16 in d_out (consumed by attn before gemm_o overwrites);
    // attn output aliases Q.
    ushort_t* Qb = (ushort_t*)d_ws;
    ushort_t* Kb = Qb + NELEM;
    ushort_t* Vb = (ushort_t*)d_out;
    ushort_t* Ob = Qb;

    const bool wfit = ws_size >= (2 * NELEM + 4 * WELEM) * sizeof(ushort_t);

    if (wfit) {
        // fp16 transposed weights in ws tail (no input mutation)
        ushort_t* T = Kb + NELEM;
        ushort_t* WtQ = T;
        ushort_t* WtK = T + WELEM;
        ushort_t* WtV = T + 2 * WELEM;
        ushort_t* WtO = T + 3 * WELEM;

        transpose_cvt4<<<dim3(16, 16, 4), blk, 0, stream>>>(
            Wq, Wk, Wv, Wo, WtQ, WtK, WtV, WtO);

        gemm_qkv<ushort_t><<<dim3(768), blk, 0, stream>>>(
            src, tgt, WtQ, WtK, WtV, bq, bk, bv, Qb, Kb, Vb);

        if (ib == 8)
            attn_kernel<long long><<<dim3(B_ * HW_), blk, 0, stream>>>(
                Qb, Kb, Vb, (const long long*)idxp, wtp, Ob);
        else
            attn_kernel<int><<<dim3(B_ * HW_), blk, 0, stream>>>(
                Qb, Kb, Vb, (const int*)idxp, wtp, Ob);

        if (ob == 2)
            gemm_o<ushort_t, ushort_t, true><<<dim3(512), blk, 0, stream>>>(
                Ob, WtO, bo, (ushort_t*)d_out);
        else
            gemm_o<ushort_t, float, false><<<dim3(512), blk, 0, stream>>>(
                Ob, WtO, bo, (float*)d_out);
    } else {
        // fallback: in-place fp32 transpose, fp32-B GEMMs
        transpose_inplace4_f32<<<dim3(136, 4), blk, 0, stream>>>(Wq, Wk, Wv, Wo);

        gemm_qkv<float><<<dim3(768), blk, 0, stream>>>(
            src, tgt, Wq, Wk, Wv, bq, bk, bv, Qb, Kb, Vb);

        if (ib == 8)
            attn_kernel<long long><<<dim3(B_ * HW_), blk, 0, stream>>>(
                Qb, Kb, Vb, (const long long*)idxp, wtp, Ob);
        else
            attn_kernel<int><<<dim3(B_ * HW_), blk, 0, stream>>>(
                Qb, Kb, Vb, (const int*)idxp, wtp, Ob);

        if (ob == 2)
            gemm_o<float, ushort_t, true><<<dim3(512), blk, 0, stream>>>(
                Ob, Wo, bo, (ushort_t*)d_out);
        else
            gemm_o<float, float, false><<<dim3(512), blk, 0, stream>>>(
                Ob, Wo, bo, (float*)d_out);
    }
}

// Round 4
// 177.996 us; speedup vs baseline: 1.0575x; 1.0220x over previous
//
#include <hip/hip_runtime.h>
#include <hip/hip_bf16.h>
#include <stdint.h>
#include <type_traits>

// Problem constants
#define B_    2
#define HW_   4096
#define NTGT_ 4096
#define C_    512
#define H_    8
#define KNN_  32
#define DH_   64
#define M_    (B_ * HW_)

typedef unsigned short ushort_t;
typedef _Float16 f16x8 __attribute__((ext_vector_type(8)));
typedef __fp16 hf2 __attribute__((ext_vector_type(2)));
typedef float floatx4 __attribute__((ext_vector_type(4)));

// ---- fp16 helpers (intermediates are IEEE fp16: more mantissa than bf16)
__device__ __forceinline__ uint32_t pkh(float x, float y) {
    union { hf2 h; uint32_t u; } c;
    c.h = __builtin_amdgcn_cvt_pkrtz(x, y);   // v_cvt_pkrtz_f16_f32
    return c.u;
}
__device__ __forceinline__ ushort_t f2h(float f) {
    return (ushort_t)(pkh(f, 0.f) & 0xffffu);
}
__device__ __forceinline__ float h2f(ushort_t u) {
    union { ushort_t s; __fp16 h; } x;
    x.s = u;
    return (float)x.h;                         // v_cvt_f32_f16
}
// bf16 round-to-nearest (final-output defensive path only)
__device__ __forceinline__ ushort_t f2b(float f) {
    union { float f; uint32_t i; } x;
    x.f = f;
    uint32_t r = x.i + 0x7fffu + ((x.i >> 16) & 1u);
    return (ushort_t)(r >> 16);
}
// 2-way fp16 dot with f32 accumulate: v_dot2_f32_f16
__device__ __forceinline__ float dot2acc(uint32_t a, uint32_t b, float c) {
#if __has_builtin(__builtin_amdgcn_fdot2)
    union { uint32_t u; hf2 h; } xa, xb;
    xa.u = a; xb.u = b;
    return __builtin_amdgcn_fdot2(xa.h, xb.h, c, false);
#else
    c = fmaf(h2f((ushort_t)(a & 0xffffu)), h2f((ushort_t)(b & 0xffffu)), c);
    return fmaf(h2f((ushort_t)(a >> 16)), h2f((ushort_t)(b >> 16)), c);
#endif
}
__device__ __forceinline__ uint4 pack8(const float4& a, const float4& b) {
    return make_uint4(pkh(a.x, a.y), pkh(a.z, a.w), pkh(b.x, b.y), pkh(b.z, b.w));
}

// ---------------------------------------------------------------------------
// Out-of-place transpose+convert: T_fp16[n][k] = W_fp32[k][n], 4 matrices.
// No input mutation. grid (16,16,4).
// ---------------------------------------------------------------------------
__global__ __launch_bounds__(256) void transpose_cvt4(
    const float* __restrict__ W0, const float* __restrict__ W1,
    const float* __restrict__ W2, const float* __restrict__ W3,
    ushort_t* __restrict__ T0, ushort_t* __restrict__ T1,
    ushort_t* __restrict__ T2, ushort_t* __restrict__ T3) {
    __shared__ float tile[32][33];

    const float* W = (blockIdx.z == 0) ? W0 : (blockIdx.z == 1) ? W1
                     : (blockIdx.z == 2) ? W2 : W3;
    ushort_t* T = (blockIdx.z == 0) ? T0 : (blockIdx.z == 1) ? T1
                  : (blockIdx.z == 2) ? T2 : T3;

    const int k0 = blockIdx.x * 32;
    const int n0 = blockIdx.y * 32;
    const int t = threadIdx.x;
    const int r = t >> 3;
    const int c0 = (t & 7) * 4;

    float4 d = *(const float4*)&W[(size_t)(k0 + r) * 512 + n0 + c0];
    tile[r][c0 + 0] = d.x; tile[r][c0 + 1] = d.y;
    tile[r][c0 + 2] = d.z; tile[r][c0 + 3] = d.w;
    __syncthreads();

    uint2 o;
    o.x = pkh(tile[c0 + 0][r], tile[c0 + 1][r]);
    o.y = pkh(tile[c0 + 2][r], tile[c0 + 3][r]);
    *(uint2*)&T[(size_t)(n0 + r) * 512 + k0 + c0] = o;
}

// ---------------------------------------------------------------------------
// IN-PLACE fp32 transpose fallback (if ws can't hold fp16 weights).
// ---------------------------------------------------------------------------
__global__ __launch_bounds__(256) void transpose_inplace4_f32(
    float* W0, float* W1, float* W2, float* W3) {
    __shared__ float ta[32][33];
    __shared__ float tb[32][33];

    float* W = (blockIdx.y == 0) ? W0 : (blockIdx.y == 1) ? W1
               : (blockIdx.y == 2) ? W2 : W3;

    int p = blockIdx.x;
    int i = 0, acc = 0;
    while (acc + (16 - i) <= p) { acc += 16 - i; ++i; }
    const int j = i + (p - acc);

    const int t = threadIdx.x;
    const int r = t >> 3;
    const int c0 = (t & 7) * 4;

    {
        float4 d = *(const float4*)&W[(size_t)(i * 32 + r) * 512 + j * 32 + c0];
        ta[r][c0 + 0] = d.x; ta[r][c0 + 1] = d.y;
        ta[r][c0 + 2] = d.z; ta[r][c0 + 3] = d.w;
    }
    if (i != j) {
        float4 d = *(const float4*)&W[(size_t)(j * 32 + r) * 512 + i * 32 + c0];
        tb[r][c0 + 0] = d.x; tb[r][c0 + 1] = d.y;
        tb[r][c0 + 2] = d.z; tb[r][c0 + 3] = d.w;
    }
    __syncthreads();

    *(float4*)&W[(size_t)(j * 32 + r) * 512 + i * 32 + c0] =
        make_float4(ta[c0 + 0][r], ta[c0 + 1][r], ta[c0 + 2][r], ta[c0 + 3][r]);
    if (i != j)
        *(float4*)&W[(size_t)(i * 32 + r) * 512 + j * 32 + c0] =
            make_float4(tb[c0 + 0][r], tb[c0 + 1][r], tb[c0 + 2][r], tb[c0 + 3][r]);
}

// ---------------------------------------------------------------------------
// MFMA GEMM body: 128(M) x BN(N) tile, BK=32, prefetch-pipelined K-loop.
// 4 waves 2x2; wave region 64 x BN/2 -> 4 x (BN/32) MFMAs of 16x16x32 f16.
// AT = fp32 (cvt via v_cvt_pkrtz) or 16-bit raw. Output: f32 / fp16 / bf16.
// ---------------------------------------------------------------------------
template <typename AT, typename BT, typename OT, int BN, bool OBF16>
__device__ __forceinline__ void gemm_body(const AT* __restrict__ A,
                                          const BT* __restrict__ Wt,
                                          const float* __restrict__ bias,
                                          OT* __restrict__ O,
                                          int bm, int bn) {
    constexpr int NJ = BN / 32;          // MFMAs in n per wave
    __shared__ ushort_t As[128][40];     // [m][k] fp16, 80B stride
    __shared__ ushort_t Bs[BN][40];      // [n][k] fp16

    const int t = threadIdx.x;
    const int lr = t >> 2;        // 0..63
    const int lc = (t & 3) * 8;   // 0,8,16,24

    const int lane = t & 63;
    const int wv = t >> 6;
    const int wr = (wv >> 1) * 64;
    const int wc = (wv & 1) * (BN / 2);
    const int r16 = lane & 15;
    const int quad = lane >> 4;

    floatx4 acc[4][NJ] = {};

    float4 fa0, fa1, fa2, fa3, fb0, fb1, fb2, fb3;
    uint4 ua0, ua1, ub0, ub1;

    // prefetch kt = 0
    if constexpr (std::is_same<AT, float>::value) {
        const float* p0 = &A[(size_t)(bm + lr) * 512 + lc];
        const float* p1 = &A[(size_t)(bm + lr + 64) * 512 + lc];
        fa0 = *(const float4*)p0; fa1 = *(const float4*)(p0 + 4);
        fa2 = *(const float4*)p1; fa3 = *(const float4*)(p1 + 4);
    } else {
        ua0 = *(const uint4*)&A[(size_t)(bm + lr) * 512 + lc];
        ua1 = *(const uint4*)&A[(size_t)(bm + lr + 64) * 512 + lc];
    }
    if constexpr (std::is_same<BT, float>::value) {
        const float* p0 = &Wt[(size_t)(bn + lr) * 512 + lc];
        fb0 = *(const float4*)p0; fb1 = *(const float4*)(p0 + 4);
        if constexpr (BN == 128) {
            const float* p1 = &Wt[(size_t)(bn + lr + 64) * 512 + lc];
            fb2 = *(const float4*)p1; fb3 = *(const float4*)(p1 + 4);
        }
    } else {
        ub0 = *(const uint4*)&Wt[(size_t)(bn + lr) * 512 + lc];
        if constexpr (BN == 128)
            ub1 = *(const uint4*)&Wt[(size_t)(bn + lr + 64) * 512 + lc];
    }

    for (int kt = 0; kt < 512; kt += 32) {
        __syncthreads();  // prior iteration's fragment reads complete
        if constexpr (std::is_same<AT, float>::value) {
            *(uint4*)&As[lr][lc] = pack8(fa0, fa1);
            *(uint4*)&As[lr + 64][lc] = pack8(fa2, fa3);
        } else {
            *(uint4*)&As[lr][lc] = ua0;
            *(uint4*)&As[lr + 64][lc] = ua1;
        }
        if constexpr (std::is_same<BT, float>::value) {
            *(uint4*)&Bs[lr][lc] = pack8(fb0, fb1);
            if constexpr (BN == 128) *(uint4*)&Bs[lr + 64][lc] = pack8(fb2, fb3);
        } else {
            *(uint4*)&Bs[lr][lc] = ub0;
            if constexpr (BN == 128) *(uint4*)&Bs[lr + 64][lc] = ub1;
        }
        __syncthreads();

        if (kt + 32 < 512) {  // issue next-tile loads; wait lands at publish
            const int k2 = kt + 32;
            if constexpr (std::is_same<AT, float>::value) {
                const float* p0 = &A[(size_t)(bm + lr) * 512 + k2 + lc];
                const float* p1 = &A[(size_t)(bm + lr + 64) * 512 + k2 + lc];
                fa0 = *(const float4*)p0; fa1 = *(const float4*)(p0 + 4);
                fa2 = *(const float4*)p1; fa3 = *(const float4*)(p1 + 4);
            } else {
                ua0 = *(const uint4*)&A[(size_t)(bm + lr) * 512 + k2 + lc];
                ua1 = *(const uint4*)&A[(size_t)(bm + lr + 64) * 512 + k2 + lc];
            }
            if constexpr (std::is_same<BT, float>::value) {
                const float* p0 = &Wt[(size_t)(bn + lr) * 512 + k2 + lc];
                fb0 = *(const float4*)p0; fb1 = *(const float4*)(p0 + 4);
                if constexpr (BN == 128) {
                    const float* p1 = &Wt[(size_t)(bn + lr + 64) * 512 + k2 + lc];
                    fb2 = *(const float4*)p1; fb3 = *(const float4*)(p1 + 4);
                }
            } else {
                ub0 = *(const uint4*)&Wt[(size_t)(bn + lr) * 512 + k2 + lc];
                if constexpr (BN == 128)
                    ub1 = *(const uint4*)&Wt[(size_t)(bn + lr + 64) * 512 + k2 + lc];
            }
        }

        f16x8 af[4], bf[NJ];
#pragma unroll
        for (int i = 0; i < 4; ++i)
            af[i] = *(const f16x8*)&As[wr + i * 16 + r16][quad * 8];
#pragma unroll
        for (int j = 0; j < NJ; ++j)
            bf[j] = *(const f16x8*)&Bs[wc + j * 16 + r16][quad * 8];
#pragma unroll
        for (int i = 0; i < 4; ++i)
#pragma unroll
            for (int j = 0; j < NJ; ++j)
                acc[i][j] = __builtin_amdgcn_mfma_f32_16x16x32_f16(
                    af[i], bf[j], acc[i][j], 0, 0, 0);
    }

    // D layout: col=lane&15, row=quad*4+reg [m89]
#pragma unroll
    for (int j = 0; j < NJ; ++j) {
        const int col = bn + wc + j * 16 + r16;
        const float bj = bias[col];
#pragma unroll
        for (int i = 0; i < 4; ++i) {
            const int row = bm + wr + i * 16 + quad * 4;
#pragma unroll
            for (int r = 0; r < 4; ++r) {
                float v = acc[i][j][r] + bj;
                if constexpr (std::is_same<OT, float>::value)
                    O[(size_t)(row + r) * 512 + col] = v;
                else if constexpr (OBF16)
                    O[(size_t)(row + r) * 512 + col] = f2b(v);
                else
                    O[(size_t)(row + r) * 512 + col] = f2h(v);
            }
        }
    }
}

// Fused Q/K/V projection: 128x128 tiles, XCD-swizzled 1D grid of 768 blocks.
template <typename BT>
__global__ __launch_bounds__(256, 3) void gemm_qkv(
    const float* __restrict__ src, const float* __restrict__ tgt,
    const BT* __restrict__ WtQ, const BT* __restrict__ WtK,
    const BT* __restrict__ WtV,
    const float* __restrict__ bq, const float* __restrict__ bk,
    const float* __restrict__ bv,
    ushort_t* __restrict__ Qb, ushort_t* __restrict__ Kb,
    ushort_t* __restrict__ Vb) {
    const int id = blockIdx.x;
    const int xcd = id & 7;
    const int g = id >> 3;        // 0..95
    const int mgrp = g / 12;      // 0..7
    const int r = g % 12;
    const int z = r >> 2;         // 0..2
    const int bn = (r & 3) * 128;
    const int bm = (xcd + 8 * mgrp) * 128;

    const float* A = (z == 0) ? src : tgt;
    const BT* Wt = (z == 0) ? WtQ : (z == 1) ? WtK : WtV;
    const float* bias = (z == 0) ? bq : (z == 1) ? bk : bv;
    ushort_t* O = (z == 0) ? Qb : (z == 1) ? Kb : Vb;
    gemm_body<float, BT, ushort_t, 128, false>(A, Wt, bias, O, bm, bn);
}

// Output projection: 128x64 tiles, XCD-swizzled 1D grid of 512 blocks.
template <typename BT, typename OT, bool OBF16>
__global__ __launch_bounds__(256, 4) void gemm_o(const ushort_t* __restrict__ A,
                                                 const BT* __restrict__ Wt,
                                                 const float* __restrict__ bias,
                                                 OT* __restrict__ O) {
    const int id = blockIdx.x;
    const int xcd = id & 7;
    const int g = id >> 3;        // 0..63
    const int mgrp = g >> 3;      // 0..7
    const int bn = (g & 7) * 64;
    const int bm = (xcd + 8 * mgrp) * 128;
    gemm_body<ushort_t, BT, OT, 64, OBF16>(A, Wt, bias, O, bm, bn);
}

// ---------------------------------------------------------------------------
// Gather attention — v4: all-loads-upfront deep register pipeline.
// No setup barrier: each thread direct-loads its own idx (2), wts (2), and
// Q fragment (4 x uint4, 16-way lane-dup -> L1 broadcast). After the single
// idx->gather-address hop, K0-15/K16-31/V0-15 (12 x uint4 regs) issue at
// once; V16-31 reuses the K0-15 regs right after their publish. Only ONE
// load-arrival wait (K0-15) is exposed; later publishes find data arrived.
// 7 barriers. O aliases Q (same-row only). XCD batch swizzle unchanged.
// ---------------------------------------------------------------------------
#define KVSTRIDE 520
template <typename IT>
__global__ __launch_bounds__(256, 5) void attn_kernel(
    const ushort_t* __restrict__ Q, const ushort_t* __restrict__ K,
    const ushort_t* __restrict__ V, const IT* __restrict__ idx,
    const float* __restrict__ wts, ushort_t* O) {
    __shared__ ushort_t kvs[16][KVSTRIDE];  // 16-row staging buffer
    __shared__ float ps[H_][KNN_];

    const int t = threadIdx.x;
    const int id = blockIdx.x;
    const int xcd = id & 7;
    const int slot = id >> 3;
    const int bt = xcd >> 2;
    const int bq = bt * HW_ + (xcd & 3) * 1024 + slot;
    const size_t qoff = (size_t)bq * C_;

    const int h = t >> 5;
    const int l5 = t & 31;
    const int nl = l5 & 15;
    const int half = l5 >> 4;
    const int koff = h * 64 + half * 32;
    const int prow = t >> 4;          // staging row 0..15 (16 lanes/row)
    const int pcol = (t & 15) * 8;    // element offset; +128 steps cover 512

    // --- issue idx first (gather addresses depend on it), then w / Q frag
    const IT* ibp = idx + (size_t)bq * KNN_;
    const int i0 = (int)ibp[prow];
    const int i1 = (int)ibp[prow + 16];
    const float w0 = wts[(size_t)bq * KNN_ + nl];
    const float w1 = wts[(size_t)bq * KNN_ + nl + 16];
    const ushort_t* qp = Q + qoff + koff;
    const uint4 q0 = *(const uint4*)(qp);
    const uint4 q1 = *(const uint4*)(qp + 8);
    const uint4 q2 = *(const uint4*)(qp + 16);
    const uint4 q3 = *(const uint4*)(qp + 24);

    const ushort_t* Kbase = K + (size_t)bt * NTGT_ * C_;
    const ushort_t* Vbase = V + (size_t)bt * NTGT_ * C_;

    uint4 a0, a1, a2, a3, b0, b1, b2, b3, c0, c1, c2, c3;
    {   // K rows 0-15
        const ushort_t* p = Kbase + (size_t)i0 * C_ + pcol;
        a0 = *(const uint4*)(p);       a1 = *(const uint4*)(p + 128);
        a2 = *(const uint4*)(p + 256); a3 = *(const uint4*)(p + 384);
    }
    {   // K rows 16-31
        const ushort_t* p = Kbase + (size_t)i1 * C_ + pcol;
        b0 = *(const uint4*)(p);       b1 = *(const uint4*)(p + 128);
        b2 = *(const uint4*)(p + 256); b3 = *(const uint4*)(p + 384);
    }
    {   // V rows 0-15
        const ushort_t* p = Vbase + (size_t)i0 * C_ + pcol;
        c0 = *(const uint4*)(p);       c1 = *(const uint4*)(p + 128);
        c2 = *(const uint4*)(p + 256); c3 = *(const uint4*)(p + 384);
    }
    // publish K rows 0-15 (vmcnt waits on a0..a3 only)
    *(uint4*)&kvs[prow][pcol + 0]   = a0;
    *(uint4*)&kvs[prow][pcol + 128] = a1;
    *(uint4*)&kvs[prow][pcol + 256] = a2;
    *(uint4*)&kvs[prow][pcol + 384] = a3;
    {   // reuse a-regs: issue V rows 16-31
        const ushort_t* p = Vbase + (size_t)i1 * C_ + pcol;
        a0 = *(const uint4*)(p);       a1 = *(const uint4*)(p + 128);
        a2 = *(const uint4*)(p + 256); a3 = *(const uint4*)(p + 384);
    }
    __syncthreads();  // (1) K rows 0-15 staged

    float l0, l1;
    {
        uint4 kv0 = *(const uint4*)&kvs[nl][koff + 0];
        uint4 kv1 = *(const uint4*)&kvs[nl][koff + 8];
        uint4 kv2 = *(const uint4*)&kvs[nl][koff + 16];
        uint4 kv3 = *(const uint4*)&kvs[nl][koff + 24];
        float da = 0.f, db = 0.f;
        da = dot2acc(kv0.x, q0.x, da); da = dot2acc(kv0.y, q0.y, da);
        da = dot2acc(kv0.z, q0.z, da); da = dot2acc(kv0.w, q0.w, da);
        db = dot2acc(kv1.x, q1.x, db); db = dot2acc(kv1.y, q1.y, db);
        db = dot2acc(kv1.z, q1.z, db); db = dot2acc(kv1.w, q1.w, db);
        da = dot2acc(kv2.x, q2.x, da); da = dot2acc(kv2.y, q2.y, da);
        da = dot2acc(kv2.z, q2.z, da); da = dot2acc(kv2.w, q2.w, da);
        db = dot2acc(kv3.x, q3.x, db); db = dot2acc(kv3.y, q3.y, db);
        db = dot2acc(kv3.z, q3.z, db); db = dot2acc(kv3.w, q3.w, db);
        float dot = da + db;
        dot += __shfl_xor(dot, 16);   // combine halves: full 64-elem dot
        l0 = dot * 0.125f + w0;
    }
    __syncthreads();  // (2) dot-A reads complete
    // publish K rows 16-31 (long since arrived)
    *(uint4*)&kvs[prow][pcol + 0]   = b0;
    *(uint4*)&kvs[prow][pcol + 128] = b1;
    *(uint4*)&kvs[prow][pcol + 256] = b2;
    *(uint4*)&kvs[prow][pcol + 384] = b3;
    __syncthreads();  // (3) K rows 16-31 staged
    {
        uint4 kv0 = *(const uint4*)&kvs[nl][koff + 0];
        uint4 kv1 = *(const uint4*)&kvs[nl][koff + 8];
        uint4 kv2 = *(const uint4*)&kvs[nl][koff + 16];
        uint4 kv3 = *(const uint4*)&kvs[nl][koff + 24];
        float da = 0.f, db = 0.f;
        da = dot2acc(kv0.x, q0.x, da); da = dot2acc(kv0.y, q0.y, da);
        da = dot2acc(kv0.z, q0.z, da); da = dot2acc(kv0.w, q0.w, da);
        db = dot2acc(kv1.x, q1.x, db); db = dot2acc(kv1.y, q1.y, db);
        db = dot2acc(kv1.z, q1.z, db); db = dot2acc(kv1.w, q1.w, db);
        da = dot2acc(kv2.x, q2.x, da); da = dot2acc(kv2.y, q2.y, da);
        da = dot2acc(kv2.z, q2.z, da); da = dot2acc(kv2.w, q2.w, da);
        db = dot2acc(kv3.x, q3.x, db); db = dot2acc(kv3.y, q3.y, db);
        db = dot2acc(kv3.z, q3.z, db); db = dot2acc(kv3.w, q3.w, db);
        float dot = da + db;
        dot += __shfl_xor(dot, 16);
        l1 = dot * 0.125f + w1;
    }
    // softmax over 32 logits; each n present in exactly 2 lanes of the group
    {
        float m = fmaxf(l0, l1);
#pragma unroll
        for (int o = 16; o > 0; o >>= 1) m = fmaxf(m, __shfl_xor(m, o));
        float e0 = __expf(l0 - m), e1 = __expf(l1 - m);
        float s = e0 + e1;
#pragma unroll
        for (int o = 16; o > 0; o >>= 1) s += __shfl_xor(s, o);
        const float inv = 2.0f / s;   // duplicates double-count: exact /2
        ps[h][nl] = e0 * inv;         // duplicate lanes write same value
        ps[h][nl + 16] = e1 * inv;
    }
    __syncthreads();  // (4) dot-B reads + ps writes complete
    // publish V rows 0-15
    *(uint4*)&kvs[prow][pcol + 0]   = c0;
    *(uint4*)&kvs[prow][pcol + 128] = c1;
    *(uint4*)&kvs[prow][pcol + 256] = c2;
    *(uint4*)&kvs[prow][pcol + 384] = c3;
    __syncthreads();  // (5) V rows 0-15 staged

    const int d2 = l5 * 2;
    float f0 = 0.f, f1 = 0.f;
#pragma unroll
    for (int nn = 0; nn < 16; ++nn) {
        uint32_t vv = *(const uint32_t*)&kvs[nn][h * DH_ + d2];
        float p = ps[h][nn];
        f0 = fmaf(p, h2f((ushort_t)(vv & 0xffffu)), f0);
        f1 = fmaf(p, h2f((ushort_t)(vv >> 16)), f1);
    }
    __syncthreads();  // (6) PV-A reads complete
    // publish V rows 16-31
    *(uint4*)&kvs[prow][pcol + 0]   = a0;
    *(uint4*)&kvs[prow][pcol + 128] = a1;
    *(uint4*)&kvs[prow][pcol + 256] = a2;
    *(uint4*)&kvs[prow][pcol + 384] = a3;
    __syncthreads();  // (7) V rows 16-31 staged
#pragma unroll
    for (int nn = 0; nn < 16; ++nn) {
        uint32_t vv = *(const uint32_t*)&kvs[nn][h * DH_ + d2];
        float p = ps[h][nn + 16];
        f0 = fmaf(p, h2f((ushort_t)(vv & 0xffffu)), f0);
        f1 = fmaf(p, h2f((ushort_t)(vv >> 16)), f1);
    }
    *(uint32_t*)(O + qoff + h * DH_ + d2) = pkh(f0, f1);
}

// ---------------------------------------------------------------------------
static int elem_bytes(const void* p, size_t n, int dflt) {
    size_t sz = 0;
    hipError_t err = hipPointerGetAttribute(
        &sz, HIP_POINTER_ATTRIBUTE_RANGE_SIZE, (hipDeviceptr_t)(uintptr_t)p);
    if (err == hipSuccess && sz >= n && (sz % n) == 0) {
        size_t b = sz / n;
        if (b == 2 || b == 4 || b == 8) return (int)b;
    }
    return dflt;
}

extern "C" void kernel_launch(void* const* d_in, const int* in_sizes, int n_in,
                              void* d_out, int out_size, void* d_ws, size_t ws_size,
                              hipStream_t stream) {
    const float* src  = (const float*)d_in[0];
    const float* tgt  = (const float*)d_in[1];
    const void*  idxp = d_in[2];
    const float* wtp  = (const float*)d_in[3];
    float* Wq = (float*)d_in[4];  const float* bq = (const float*)d_in[5];
    float* Wk = (float*)d_in[6];  const float* bk = (const float*)d_in[7];
    float* Wv = (float*)d_in[8];  const float* bv = (const float*)d_in[9];
    float* Wo = (float*)d_in[10]; const float* bo = (const float*)d_in[11];

    const size_t NELEM = (size_t)M_ * C_;          // 4,194,304
    const size_t WELEM = (size_t)C_ * C_;          // 262,144
    const size_t NIDX  = (size_t)B_ * HW_ * KNN_;

    const int ib = elem_bytes(idxp, NIDX, 4);
    const int ob = elem_bytes(d_out, NELEM, 4);

    dim3 blk(256);

    // ws: Q fp16 [0,8MB) | K fp16 [8,16MB) | optional fp16 Wt x4 [16,18MB).
    // V fp16 in d_out (consumed by attn before gemm_o overwrites);
    // attn output aliases Q.
    ushort_t* Qb = (ushort_t*)d_ws;
    ushort_t* Kb = Qb + NELEM;
    ushort_t* Vb = (ushort_t*)d_out;
    ushort_t* Ob = Qb;

    const bool wfit = ws_size >= (2 * NELEM + 4 * WELEM) * sizeof(ushort_t);

    if (wfit) {
        // fp16 transposed weights in ws tail (no input mutation)
        ushort_t* T = Kb + NELEM;
        ushort_t* WtQ = T;
        ushort_t* WtK = T + WELEM;
        ushort_t* WtV = T + 2 * WELEM;
        ushort_t* WtO = T + 3 * WELEM;

        transpose_cvt4<<<dim3(16, 16, 4), blk, 0, stream>>>(
            Wq, Wk, Wv, Wo, WtQ, WtK, WtV, WtO);

        gemm_qkv<ushort_t><<<dim3(768), blk, 0, stream>>>(
            src, tgt, WtQ, WtK, WtV, bq, bk, bv, Qb, Kb, Vb);

        if (ib == 8)
            attn_kernel<long long><<<dim3(B_ * HW_), blk, 0, stream>>>(
                Qb, Kb, Vb, (const long long*)idxp, wtp, Ob);
        else
            attn_kernel<int><<<dim3(B_ * HW_), blk, 0, stream>>>(
                Qb, Kb, Vb, (const int*)idxp, wtp, Ob);

        if (ob == 2)
            gemm_o<ushort_t, ushort_t, true><<<dim3(512), blk, 0, stream>>>(
                Ob, WtO, bo, (ushort_t*)d_out);
        else
            gemm_o<ushort_t, float, false><<<dim3(512), blk, 0, stream>>>(
                Ob, WtO, bo, (float*)d_out);
    } else {
        // fallback: in-place fp32 transpose, fp32-B GEMMs
        transpose_inplace4_f32<<<dim3(136, 4), blk, 0, stream>>>(Wq, Wk, Wv, Wo);

        gemm_qkv<float><<<dim3(768), blk, 0, stream>>>(
            src, tgt, Wq, Wk, Wv, bq, bk, bv, Qb, Kb, Vb);

        if (ib == 8)
            attn_kernel<long long><<<dim3(B_ * HW_), blk, 0, stream>>>(
                Qb, Kb, Vb, (const long long*)idxp, wtp, Ob);
        else
            attn_kernel<int><<<dim3(B_ * HW_), blk, 0, stream>>>(
                Qb, Kb, Vb, (const int*)idxp, wtp, Ob);

        if (ob == 2)
            gemm_o<float, ushort_t, true><<<dim3(512), blk, 0, stream>>>(
                Ob, Wo, bo, (ushort_t*)d_out);
        else
            gemm_o<float, float, false><<<dim3(512), blk, 0, stream>>>(
                Ob, Wo, bo, (float*)d_out);
    }
}